// Round 1
// baseline (982.425 us; speedup 1.0000x reference)
//
#include <hip/hip_runtime.h>
#include <hip/hip_bf16.h>
#include <math.h>

#define BSZ 8
#define SEQ 1024
#define EMB 512
#define NH 8
#define HD 64
#define UE 6
#define QKSCALE 0.125f

#define FMA16(a, b, acc)                                                                 \
  acc[0][0] += a.x * b.x; acc[0][1] += a.x * b.y; acc[0][2] += a.x * b.z; acc[0][3] += a.x * b.w; \
  acc[1][0] += a.y * b.x; acc[1][1] += a.y * b.y; acc[1][2] += a.y * b.z; acc[1][3] += a.y * b.w; \
  acc[2][0] += a.z * b.x; acc[2][1] += a.z * b.y; acc[2][2] += a.z * b.z; acc[2][3] += a.z * b.w; \
  acc[3][0] += a.w * b.x; acc[3][1] += a.w * b.y; acc[3][2] += a.w * b.z; acc[3][3] += a.w * b.w;

// ---------------- K1: QKV projection ----------------
// C[m,c] = sum_e x[m,e] * W[c,e]; scatter to [b,h,n,d]. Grid (128 mtiles, 8 ctiles, 3)
__global__ __launch_bounds__(256) void qkv_proj_kernel(
    const float* __restrict__ x,
    const float* __restrict__ Wq, const float* __restrict__ Wk, const float* __restrict__ Wv,
    float* __restrict__ Q, float* __restrict__ K, float* __restrict__ V) {
  const int mt = blockIdx.x, nt = blockIdx.y, wsel = blockIdx.z;
  const float* __restrict__ W = (wsel == 0) ? Wq : ((wsel == 1) ? Wk : Wv);
  float* __restrict__ Out = (wsel == 0) ? Q : ((wsel == 1) ? K : V);
  __shared__ float As[32][68];  // [e][m]
  __shared__ float Bs[32][68];  // [e][c]
  const int t = threadIdx.x;
  const int m0 = mt * 64, c0 = nt * 64;
  const int lr = t >> 5, lc = t & 31;
  const int tm = (t >> 4) << 2, tn = (t & 15) << 2;
  float acc[4][4] = {};
  for (int e0 = 0; e0 < EMB; e0 += 32) {
#pragma unroll
    for (int r = 0; r < 8; ++r) {
      const int row = lr + r * 8;
      As[lc][row] = x[(size_t)(m0 + row) * EMB + e0 + lc];
      Bs[lc][row] = W[(size_t)(c0 + row) * EMB + e0 + lc];
    }
    __syncthreads();
#pragma unroll 8
    for (int kk = 0; kk < 32; ++kk) {
      const float4 a = *(const float4*)&As[kk][tm];
      const float4 b = *(const float4*)&Bs[kk][tn];
      FMA16(a, b, acc)
    }
    __syncthreads();
  }
  const int h = c0 >> 6;  // tile spans exactly one head (64 cols)
#pragma unroll
  for (int i = 0; i < 4; ++i) {
    const int m = m0 + tm + i;
    const int b = m >> 10, n = m & 1023;
    float* op = Out + (((size_t)(b * NH + h) * SEQ + n) << 6) + tn;
    *(float4*)op = make_float4(acc[i][0], acc[i][1], acc[i][2], acc[i][3]);
  }
}

// ---------------- K2: scores = QK^T*scale + ub, masked ----------------
// Grid: x = h + 8*kt (h fastest for u L3 reuse), y = qt, z = b. Block 256.
__global__ __launch_bounds__(256) void scores_kernel(
    const float* __restrict__ Qb, const float* __restrict__ Kb,
    const float* __restrict__ u, const int* __restrict__ umask,
    const float* __restrict__ Wu, const float* __restrict__ bu,
    float* __restrict__ attn) {
  const int gx = blockIdx.x;
  const int h = gx & 7, kt = gx >> 3;
  const int qt = blockIdx.y, b = blockIdx.z;
  const int bh = b * NH + h;
  const int q0 = qt * 64, k0 = kt * 64;
  __shared__ float Qs[64][68];        // [d][q]
  __shared__ float Ks[64][68];        // [d][k]
  __shared__ unsigned char ms[64][68];  // [k][q]
  const int t = threadIdx.x;
  const float* Qp = Qb + ((size_t)bh * SEQ + q0) * HD;
  const float* Kp = Kb + ((size_t)bh * SEQ + k0) * HD;
  {
    const int d = t & 63, r0 = t >> 6;
#pragma unroll
    for (int r = 0; r < 16; ++r) {
      const int q = r0 + r * 4;
      Qs[d][q] = Qp[(size_t)q * HD + d];
      Ks[d][q] = Kp[(size_t)q * HD + d];
    }
#pragma unroll
    for (int r = 0; r < 16; ++r) {
      const int k = r0 + r * 4;
      ms[k][d] = (unsigned char)(umask[((size_t)b * SEQ + k0 + k) * SEQ + q0 + d] != 0);
    }
  }
  __syncthreads();
  const int tq = (t >> 4) << 2, tk = (t & 15) << 2;  // lanes vary k fastest -> coalesced u/attn
  float acc[4][4] = {};
#pragma unroll 16
  for (int d = 0; d < 64; ++d) {
    const float4 a = *(const float4*)&Qs[d][tq];
    const float4 bk = *(const float4*)&Ks[d][tk];
    FMA16(a, bk, acc)
  }
  float wu[UE];
#pragma unroll
  for (int i = 0; i < UE; ++i) wu[i] = Wu[h * UE + i];
  const float bub = bu[h];
#pragma unroll
  for (int qi = 0; qi < 4; ++qi) {
    const int q = q0 + tq + qi;
    float ub0 = bub, ub1 = bub, ub2 = bub, ub3 = bub;
#pragma unroll
    for (int uu = 0; uu < UE; ++uu) {
      const float4 uv = *(const float4*)&u[(((size_t)b * UE + uu) * SEQ + q) * SEQ + k0 + tk];
      ub0 += uv.x * wu[uu]; ub1 += uv.y * wu[uu];
      ub2 += uv.z * wu[uu]; ub3 += uv.w * wu[uu];
    }
    float4 sv;
    sv.x = ms[tk + 0][tq + qi] ? -INFINITY : acc[qi][0] * QKSCALE + ub0;
    sv.y = ms[tk + 1][tq + qi] ? -INFINITY : acc[qi][1] * QKSCALE + ub1;
    sv.z = ms[tk + 2][tq + qi] ? -INFINITY : acc[qi][2] * QKSCALE + ub2;
    sv.w = ms[tk + 3][tq + qi] ? -INFINITY : acc[qi][3] * QKSCALE + ub3;
    *(float4*)&attn[((size_t)bh * SEQ + q) * SEQ + k0 + tk] = sv;
  }
}

// ---------------- K3: row softmax in place ----------------
__global__ __launch_bounds__(256) void softmax_kernel(float* __restrict__ attn) {
  const size_t row = blockIdx.x;
  float4* p = reinterpret_cast<float4*>(attn + row * SEQ);
  const int t = threadIdx.x;
  float4 v = p[t];
  float m = fmaxf(fmaxf(v.x, v.y), fmaxf(v.z, v.w));
#pragma unroll
  for (int o = 32; o > 0; o >>= 1) m = fmaxf(m, __shfl_xor(m, o));
  __shared__ float redm[4], reds[4];
  const int wave = t >> 6;
  if ((t & 63) == 0) redm[wave] = m;
  __syncthreads();
  m = fmaxf(fmaxf(redm[0], redm[1]), fmaxf(redm[2], redm[3]));
  float4 e;
  e.x = __expf(v.x - m); e.y = __expf(v.y - m);
  e.z = __expf(v.z - m); e.w = __expf(v.w - m);
  float s = e.x + e.y + e.z + e.w;
#pragma unroll
  for (int o = 32; o > 0; o >>= 1) s += __shfl_xor(s, o);
  if ((t & 63) == 0) reds[wave] = s;
  __syncthreads();
  s = reds[0] + reds[1] + reds[2] + reds[3];
  const float inv = 1.0f / s;
  e.x *= inv; e.y *= inv; e.z *= inv; e.w *= inv;
  p[t] = e;
}

// ---------------- K4: ctx = attn @ V ----------------
// Grid (16 qtiles, 64 bh). C[q,d] = sum_k A[q,k] V[k,d]
__global__ __launch_bounds__(256) void pv_kernel(
    const float* __restrict__ attn, const float* __restrict__ V, float* __restrict__ ctx) {
  const int qt = blockIdx.x, bh = blockIdx.y;
  const int b = bh >> 3, h = bh & 7;
  __shared__ float As[32][68];  // [k][q]
  __shared__ float Bs[32][68];  // [k][d]
  const int t = threadIdx.x;
  const int q0 = qt * 64;
  const float* Ap = attn + ((size_t)bh * SEQ + q0) * SEQ;
  const float* Vp = V + (size_t)bh * SEQ * HD;
  const int lr = t >> 5, lc = t & 31;
  const int d_ = t & 63, kr = t >> 6;
  const int tq = (t >> 4) << 2, td = (t & 15) << 2;
  float acc[4][4] = {};
  for (int k0 = 0; k0 < SEQ; k0 += 32) {
#pragma unroll
    for (int r = 0; r < 8; ++r) {
      const int row = lr + r * 8;
      As[lc][row] = Ap[(size_t)row * SEQ + k0 + lc];
    }
#pragma unroll
    for (int r = 0; r < 8; ++r) {
      const int kk = kr + r * 4;
      Bs[kk][d_] = Vp[(size_t)(k0 + kk) * HD + d_];
    }
    __syncthreads();
#pragma unroll 8
    for (int kk = 0; kk < 32; ++kk) {
      const float4 a = *(const float4*)&As[kk][tq];
      const float4 b = *(const float4*)&Bs[kk][td];
      FMA16(a, b, acc)
    }
    __syncthreads();
  }
#pragma unroll
  for (int i = 0; i < 4; ++i) {
    const int q = q0 + tq + i;
    float* cp = ctx + (size_t)(b * SEQ + q) * EMB + h * HD + td;
    *(float4*)cp = make_float4(acc[i][0], acc[i][1], acc[i][2], acc[i][3]);
  }
}

// ---------------- K5: out = ctx @ Wo^T + bo ----------------
__global__ __launch_bounds__(256) void oproj_kernel(
    const float* __restrict__ ctx, const float* __restrict__ Wo,
    const float* __restrict__ bo, float* __restrict__ out) {
  const int mt = blockIdx.x, nt = blockIdx.y;
  __shared__ float As[32][68];
  __shared__ float Bs[32][68];
  const int t = threadIdx.x;
  const int m0 = mt * 64, c0 = nt * 64;
  const int lr = t >> 5, lc = t & 31;
  const int tm = (t >> 4) << 2, tn = (t & 15) << 2;
  float acc[4][4] = {};
  for (int e0 = 0; e0 < EMB; e0 += 32) {
#pragma unroll
    for (int r = 0; r < 8; ++r) {
      const int row = lr + r * 8;
      As[lc][row] = ctx[(size_t)(m0 + row) * EMB + e0 + lc];
      Bs[lc][row] = Wo[(size_t)(c0 + row) * EMB + e0 + lc];
    }
    __syncthreads();
#pragma unroll 8
    for (int kk = 0; kk < 32; ++kk) {
      const float4 a = *(const float4*)&As[kk][tm];
      const float4 b = *(const float4*)&Bs[kk][tn];
      FMA16(a, b, acc)
    }
    __syncthreads();
  }
#pragma unroll
  for (int i = 0; i < 4; ++i) {
    const int m = m0 + tm + i;
    float4 bias = *(const float4*)&bo[c0 + tn];
    float* op = out + (size_t)m * EMB + c0 + tn;
    *(float4*)op = make_float4(acc[i][0] + bias.x, acc[i][1] + bias.y,
                               acc[i][2] + bias.z, acc[i][3] + bias.w);
  }
}

extern "C" void kernel_launch(void* const* d_in, const int* in_sizes, int n_in,
                              void* d_out, int out_size, void* d_ws, size_t ws_size,
                              hipStream_t stream) {
  const float* x = (const float*)d_in[0];
  const float* u = (const float*)d_in[1];
  const int* umask = (const int*)d_in[2];  // bool input assumed pushed as int32
  const float* Wq = (const float*)d_in[3];
  const float* Wk = (const float*)d_in[4];
  const float* Wv = (const float*)d_in[5];
  const float* Wu = (const float*)d_in[6];
  const float* bu = (const float*)d_in[7];
  const float* Wo = (const float*)d_in[8];
  const float* bo = (const float*)d_in[9];

  float* out = (float*)d_out;
  float* attn = out + (size_t)BSZ * SEQ * EMB;  // outputs concatenated: out, then attn

  const size_t per = (size_t)BSZ * NH * SEQ * HD;  // 4,194,304 floats
  float* Q = (float*)d_ws;
  float* K = Q + per;
  float* V = K + per;
  float* ctx = V + per;  // total 67.1 MB of workspace

  qkv_proj_kernel<<<dim3(128, 8, 3), 256, 0, stream>>>(x, Wq, Wk, Wv, Q, K, V);
  scores_kernel<<<dim3(128, 16, 8), 256, 0, stream>>>(Q, K, u, umask, Wu, bu, attn);
  softmax_kernel<<<dim3(65536, 1, 1), 256, 0, stream>>>(attn);
  pv_kernel<<<dim3(16, 64), 256, 0, stream>>>(attn, V, ctx);
  oproj_kernel<<<dim3(128, 8), 256, 0, stream>>>(ctx, Wo, bo, out);
}

// Round 3
// 544.699 us; speedup vs baseline: 1.8036x; 1.8036x over previous
//
#include <hip/hip_runtime.h>
#include <hip/hip_bf16.h>
#include <math.h>

#define BSZ 8
#define SEQ 1024
#define EMB 512
#define NH 8
#define HD 64
#define UE 6
#define QKSCALE 0.125f

typedef unsigned short u16;
typedef short bf16x8 __attribute__((ext_vector_type(8)));
typedef float f32x4 __attribute__((ext_vector_type(4)));
typedef unsigned short ushort4_t __attribute__((ext_vector_type(4)));

__device__ __forceinline__ u16 f2bf(float f) {
  unsigned u = __float_as_uint(f);
  unsigned r = (u + 0x7fffu + ((u >> 16) & 1u)) >> 16;
  return (u16)r;
}
__device__ __forceinline__ void f2hl(float f, u16& hi, u16& lo) {
  hi = f2bf(f);
  float fh = __uint_as_float(((unsigned)hi) << 16);
  lo = f2bf(f - fh);
}
// vector-lane safe variant (clang can't bind refs to vector elements)
#define F2HL_V(fv, hv, lv, idx)            \
  {                                        \
    u16 _h, _l;                            \
    f2hl((fv), _h, _l);                    \
    (hv)[idx] = (short)_h;                 \
    (lv)[idx] = (short)_l;                 \
  }
__device__ __forceinline__ f32x4 mfma_bf16(bf16x8 a, bf16x8 b, f32x4 c) {
  return __builtin_amdgcn_mfma_f32_16x16x32_bf16(a, b, c, 0, 0, 0);
}

// ---------------- K0: split f32 -> (hi,lo) bf16 ----------------
__global__ __launch_bounds__(256) void split_kernel(const float* __restrict__ src,
                                                    u16* __restrict__ hi, u16* __restrict__ lo, int n4) {
  int i = blockIdx.x * 256 + threadIdx.x;
  if (i >= n4) return;
  float4 v = ((const float4*)src)[i];
  ushort4_t h, l;
  F2HL_V(v.x, h, l, 0); F2HL_V(v.y, h, l, 1);
  F2HL_V(v.z, h, l, 2); F2HL_V(v.w, h, l, 3);
  ((ushort4_t*)hi)[i] = h;
  ((ushort4_t*)lo)[i] = l;
}

// ---------------- K1: QKV projection (bf16x3 MFMA) ----------------
// grid (mt 128, h 8, wsel 3). Q/K -> hi/lo bf16 [bh][n][64]; V -> transposed bf16 Vt[bh][d][n]
__global__ __launch_bounds__(256, 4) void qkv_mfma_kernel(
    const float* __restrict__ x, const u16* __restrict__ Wsp,
    u16* __restrict__ Qhi, u16* __restrict__ Qlo,
    u16* __restrict__ Khi, u16* __restrict__ Klo, u16* __restrict__ Vt) {
  const int mt = blockIdx.x, h = blockIdx.y, wsel = blockIdx.z;
  const int m0 = mt * 64, c0 = h * 64;
  const u16* __restrict__ WH = Wsp + (size_t)wsel * 524288;
  const u16* __restrict__ WL = WH + 262144;
  __shared__ u16 AH[64][40], AL[64][40], BH[64][40], BL[64][40];
  __shared__ u16 vout[64][69];
  const int t = threadIdx.x, w = t >> 6, l = t & 63;
  const int wr = (w >> 1) * 32, wc = (w & 1) * 32;
  f32x4 acc[2][2] = {};
  const int srow = t >> 2;
  for (int e0 = 0; e0 < EMB; e0 += 32) {
    {
      const int c = (t & 3) * 8;
      float4 v0 = *(const float4*)&x[(size_t)(m0 + srow) * EMB + e0 + c];
      float4 v1 = *(const float4*)&x[(size_t)(m0 + srow) * EMB + e0 + c + 4];
      ushort4_t h0, l0, h1, l1;
      F2HL_V(v0.x, h0, l0, 0); F2HL_V(v0.y, h0, l0, 1); F2HL_V(v0.z, h0, l0, 2); F2HL_V(v0.w, h0, l0, 3);
      F2HL_V(v1.x, h1, l1, 0); F2HL_V(v1.y, h1, l1, 1); F2HL_V(v1.z, h1, l1, 2); F2HL_V(v1.w, h1, l1, 3);
      *(ushort4_t*)&AH[srow][c] = h0; *(ushort4_t*)&AH[srow][c + 4] = h1;
      *(ushort4_t*)&AL[srow][c] = l0; *(ushort4_t*)&AL[srow][c + 4] = l1;
      *(bf16x8*)&BH[srow][c] = *(const bf16x8*)&WH[(size_t)(c0 + srow) * EMB + e0 + c];
      *(bf16x8*)&BL[srow][c] = *(const bf16x8*)&WL[(size_t)(c0 + srow) * EMB + e0 + c];
    }
    __syncthreads();
    const int ar = l & 15, ach = (l >> 4) << 3;
    bf16x8 ah0 = *(bf16x8*)&AH[wr + ar][ach],      ah1 = *(bf16x8*)&AH[wr + 16 + ar][ach];
    bf16x8 al0 = *(bf16x8*)&AL[wr + ar][ach],      al1 = *(bf16x8*)&AL[wr + 16 + ar][ach];
    bf16x8 bh0 = *(bf16x8*)&BH[wc + ar][ach],      bh1 = *(bf16x8*)&BH[wc + 16 + ar][ach];
    bf16x8 bl0 = *(bf16x8*)&BL[wc + ar][ach],      bl1 = *(bf16x8*)&BL[wc + 16 + ar][ach];
    acc[0][0] = mfma_bf16(ah0, bh0, acc[0][0]); acc[0][0] = mfma_bf16(ah0, bl0, acc[0][0]); acc[0][0] = mfma_bf16(al0, bh0, acc[0][0]);
    acc[0][1] = mfma_bf16(ah0, bh1, acc[0][1]); acc[0][1] = mfma_bf16(ah0, bl1, acc[0][1]); acc[0][1] = mfma_bf16(al0, bh1, acc[0][1]);
    acc[1][0] = mfma_bf16(ah1, bh0, acc[1][0]); acc[1][0] = mfma_bf16(ah1, bl0, acc[1][0]); acc[1][0] = mfma_bf16(al1, bh0, acc[1][0]);
    acc[1][1] = mfma_bf16(ah1, bh1, acc[1][1]); acc[1][1] = mfma_bf16(ah1, bl1, acc[1][1]); acc[1][1] = mfma_bf16(al1, bh1, acc[1][1]);
    __syncthreads();
  }
  const int bb = m0 >> 10, n0 = m0 & 1023;
  if (wsel < 2) {
    u16* __restrict__ OH = wsel ? Khi : Qhi;
    u16* __restrict__ OL = wsel ? Klo : Qlo;
#pragma unroll
    for (int i = 0; i < 2; ++i)
#pragma unroll
      for (int j = 0; j < 2; ++j) {
        const int col = wc + 16 * j + (l & 15);
#pragma unroll
        for (int r = 0; r < 4; ++r) {
          const int n = n0 + wr + 16 * i + ((l >> 4) << 2) + r;
          size_t o = ((size_t)(bb * NH + h) * SEQ + n) * HD + col;
          u16 hi, lo; f2hl(acc[i][j][r], hi, lo);
          OH[o] = hi; OL[o] = lo;
        }
      }
  } else {
#pragma unroll
    for (int i = 0; i < 2; ++i)
#pragma unroll
      for (int j = 0; j < 2; ++j) {
        const int col = wc + 16 * j + (l & 15);
#pragma unroll
        for (int r = 0; r < 4; ++r)
          vout[wr + 16 * i + ((l >> 4) << 2) + r][col] = f2bf(acc[i][j][r]);
      }
    __syncthreads();
    const int d = t >> 2, nch = (t & 3) * 16;
    bf16x8 o0, o1;
#pragma unroll
    for (int i = 0; i < 8; ++i) o0[i] = (short)vout[nch + i][d];
#pragma unroll
    for (int i = 0; i < 8; ++i) o1[i] = (short)vout[nch + 8 + i][d];
    size_t dst = ((size_t)(bb * NH + h) * HD + d) * SEQ + n0 + nch;
    *(bf16x8*)&Vt[dst] = o0;
    *(bf16x8*)&Vt[dst + 8] = o1;
  }
}

// ---------------- K2: raw scores = QK^T*scale + ub (masked) ----------------
// grid (kt 16, qt 16, b 8); all 8 heads per block; u read once into registers.
__global__ __launch_bounds__(256, 4) void scores_kernel(
    const u16* __restrict__ Qhi, const u16* __restrict__ Qlo,
    const u16* __restrict__ Khi, const u16* __restrict__ Klo,
    const float* __restrict__ u, const int* __restrict__ umask,
    const float* __restrict__ Wu, const float* __restrict__ bu,
    float* __restrict__ attn) {
  const int kt = blockIdx.x, qt = blockIdx.y, b = blockIdx.z;
  const int q0 = qt * 64, k0 = kt * 64;
  __shared__ u16 KsH[64][72], KsL[64][72];
  __shared__ unsigned char ms[64][68];
  __shared__ float outl[64][68];
  const int t = threadIdx.x, w = t >> 6, l = t & 63;
  const int qb = 16 * w + ((l >> 4) << 2);  // per-lane row base (4 rows)
  const int kl = l & 15;

  // mask tile: ms[k][q] = umask[b][k0+k][q0+q]
#pragma unroll
  for (int r = 0; r < 16; ++r) {
    int idx = r * 256 + t; int k = idx >> 6, q = idx & 63;
    ms[k][q] = (unsigned char)(umask[((size_t)b * SEQ + k0 + k) * SEQ + q0 + q] != 0);
  }

  // u preload -> packed bf16 pairs (rows 2p,2p+1)
  unsigned upk[UE][4][2];
  {
    const float* ubase = u + ((size_t)b * UE * SEQ + q0 + qb) * SEQ + k0 + kl;
#pragma unroll
    for (int uu = 0; uu < UE; ++uu)
#pragma unroll
      for (int tt = 0; tt < 4; ++tt)
#pragma unroll
        for (int p = 0; p < 2; ++p) {
          const float* up = ubase + (size_t)uu * SEQ * SEQ + (size_t)(2 * p) * SEQ + 16 * tt;
          float f0 = up[0], f1 = up[SEQ];
          upk[uu][tt][p] = (unsigned)f2bf(f0) | ((unsigned)f2bf(f1) << 16);
        }
  }

  for (int h = 0; h < NH; ++h) {
    const int bh = b * NH + h;
    {
      const int row = t >> 2, c = (t & 3) * 16;
      const u16* kp = Khi + ((size_t)bh * SEQ + k0 + row) * HD + c;
      const u16* kq = Klo + ((size_t)bh * SEQ + k0 + row) * HD + c;
      *(bf16x8*)&KsH[row][c] = *(const bf16x8*)kp;
      *(bf16x8*)&KsH[row][c + 8] = *(const bf16x8*)(kp + 8);
      *(bf16x8*)&KsL[row][c] = *(const bf16x8*)kq;
      *(bf16x8*)&KsL[row][c + 8] = *(const bf16x8*)(kq + 8);
    }
    __syncthreads();
    const u16* qp = Qhi + ((size_t)bh * SEQ + q0 + 16 * w + (l & 15)) * HD + ((l >> 4) << 3);
    const u16* ql = Qlo + ((size_t)bh * SEQ + q0 + 16 * w + (l & 15)) * HD + ((l >> 4) << 3);
    bf16x8 qh0 = *(const bf16x8*)qp, qh1 = *(const bf16x8*)(qp + 32);
    bf16x8 ql0 = *(const bf16x8*)ql, ql1 = *(const bf16x8*)(ql + 32);
    float wu_[UE];
#pragma unroll
    for (int uu = 0; uu < UE; ++uu) wu_[uu] = Wu[h * UE + uu];
    const float bub = bu[h];
#pragma unroll
    for (int tt = 0; tt < 4; ++tt) {
      const int krow = tt * 16 + (l & 15), kch = (l >> 4) << 3;
      bf16x8 kh0 = *(bf16x8*)&KsH[krow][kch], kh1 = *(bf16x8*)&KsH[krow][kch + 32];
      bf16x8 kl0 = *(bf16x8*)&KsL[krow][kch], kl1 = *(bf16x8*)&KsL[krow][kch + 32];
      f32x4 acc = {0.f, 0.f, 0.f, 0.f};
      acc = mfma_bf16(qh0, kh0, acc); acc = mfma_bf16(qh1, kh1, acc);
      acc = mfma_bf16(qh0, kl0, acc); acc = mfma_bf16(qh1, kl1, acc);
      acc = mfma_bf16(ql0, kh0, acc); acc = mfma_bf16(ql1, kh1, acc);
#pragma unroll
      for (int p = 0; p < 2; ++p) {
        float ubx = bub, uby = bub;
#pragma unroll
        for (int uu = 0; uu < UE; ++uu) {
          unsigned pk = upk[uu][tt][p];
          float flo = __uint_as_float(pk << 16);
          float fhi = __uint_as_float(pk & 0xffff0000u);
          ubx = fmaf(wu_[uu], flo, ubx);
          uby = fmaf(wu_[uu], fhi, uby);
        }
#pragma unroll
        for (int e = 0; e < 2; ++e) {
          const int r = 2 * p + e;
          float v = acc[r] * QKSCALE + (e ? uby : ubx);
          if (ms[tt * 16 + kl][qb + r]) v = -INFINITY;
          outl[qb + r][tt * 16 + kl] = v;
        }
      }
    }
    __syncthreads();
    {
      const int row = t >> 2, c = (t & 3) * 16;
      float* op = attn + ((size_t)bh * SEQ + q0 + row) * SEQ + k0 + c;
      const float4* s = (const float4*)&outl[row][c];
      ((float4*)op)[0] = s[0]; ((float4*)op)[1] = s[1];
      ((float4*)op)[2] = s[2]; ((float4*)op)[3] = s[3];
    }
    __syncthreads();
  }
}

// ---------------- K3: fused softmax + PV ----------------
// grid (qt 16, bh 64). attn: raw in, softmax out (in place). ctx -> hi/lo bf16.
__global__ __launch_bounds__(256, 4) void pv_softmax_kernel(
    float* __restrict__ attn, const u16* __restrict__ Vt,
    u16* __restrict__ ctx_hi, u16* __restrict__ ctx_lo) {
  const int qt = blockIdx.x, bh = blockIdx.y;
  const int q0 = qt * 64;
  __shared__ u16 Pl[64][72], Vs[64][72];
  const int t = threadIdx.x, w = t >> 6, l = t & 63;
  const int row = t >> 2, cc = (t & 3) * 16;
  float* arow = attn + ((size_t)bh * SEQ + q0 + row) * SEQ + cc;

  // phase 1: per-row online max & sum (4 threads per row)
  float M = -INFINITY, S = 0.f;
  for (int k0 = 0; k0 < SEQ; k0 += 64) {
    float4 v0 = *(const float4*)(arow + k0);
    float4 v1 = *(const float4*)(arow + k0 + 4);
    float4 v2 = *(const float4*)(arow + k0 + 8);
    float4 v3 = *(const float4*)(arow + k0 + 12);
    float tm = fmaxf(fmaxf(fmaxf(v0.x, v0.y), fmaxf(v0.z, v0.w)),
                     fmaxf(fmaxf(v1.x, v1.y), fmaxf(v1.z, v1.w)));
    tm = fmaxf(tm, fmaxf(fmaxf(fmaxf(v2.x, v2.y), fmaxf(v2.z, v2.w)),
                         fmaxf(fmaxf(v3.x, v3.y), fmaxf(v3.z, v3.w))));
    if (tm > M) { S *= __expf(M - tm); M = tm; }
    S += __expf(v0.x - M) + __expf(v0.y - M) + __expf(v0.z - M) + __expf(v0.w - M)
       + __expf(v1.x - M) + __expf(v1.y - M) + __expf(v1.z - M) + __expf(v1.w - M)
       + __expf(v2.x - M) + __expf(v2.y - M) + __expf(v2.z - M) + __expf(v2.w - M)
       + __expf(v3.x - M) + __expf(v3.y - M) + __expf(v3.z - M) + __expf(v3.w - M);
  }
#pragma unroll
  for (int o = 1; o <= 2; o <<= 1) {
    float Mo = __shfl_xor(M, o), So = __shfl_xor(S, o);
    float Mn = fmaxf(M, Mo);
    S = S * __expf(M - Mn) + So * __expf(Mo - Mn);
    M = Mn;
  }
  const float inv = 1.0f / S;

  // phase 2: normalize + write attn + MFMA PV
  const int wr = (w >> 1) * 32, wc = (w & 1) * 32;
  f32x4 acc[2][2] = {};
  for (int k0 = 0; k0 < SEQ; k0 += 64) {
    bf16x8 p0, p1;
#pragma unroll
    for (int c4 = 0; c4 < 4; ++c4) {
      float4 v = *(const float4*)(arow + k0 + 4 * c4);
      float4 p;
      p.x = __expf(v.x - M) * inv; p.y = __expf(v.y - M) * inv;
      p.z = __expf(v.z - M) * inv; p.w = __expf(v.w - M) * inv;
      *(float4*)(arow + k0 + 4 * c4) = p;
      if (c4 < 2) {
        p0[4 * c4 + 0] = (short)f2bf(p.x); p0[4 * c4 + 1] = (short)f2bf(p.y);
        p0[4 * c4 + 2] = (short)f2bf(p.z); p0[4 * c4 + 3] = (short)f2bf(p.w);
      } else {
        p1[4 * (c4 - 2) + 0] = (short)f2bf(p.x); p1[4 * (c4 - 2) + 1] = (short)f2bf(p.y);
        p1[4 * (c4 - 2) + 2] = (short)f2bf(p.z); p1[4 * (c4 - 2) + 3] = (short)f2bf(p.w);
      }
    }
    *(bf16x8*)&Pl[row][cc] = p0;
    *(bf16x8*)&Pl[row][cc + 8] = p1;
    {
      const u16* vp = Vt + ((size_t)bh * HD + row) * SEQ + k0 + cc;
      *(bf16x8*)&Vs[row][cc] = *(const bf16x8*)vp;
      *(bf16x8*)&Vs[row][cc + 8] = *(const bf16x8*)(vp + 8);
    }
    __syncthreads();
#pragma unroll
    for (int kb = 0; kb < 2; ++kb) {
      const int kch = kb * 32 + ((l >> 4) << 3);
      bf16x8 a0 = *(bf16x8*)&Pl[wr + (l & 15)][kch];
      bf16x8 a1 = *(bf16x8*)&Pl[wr + 16 + (l & 15)][kch];
      bf16x8 b0 = *(bf16x8*)&Vs[wc + (l & 15)][kch];
      bf16x8 b1 = *(bf16x8*)&Vs[wc + 16 + (l & 15)][kch];
      acc[0][0] = mfma_bf16(a0, b0, acc[0][0]);
      acc[0][1] = mfma_bf16(a0, b1, acc[0][1]);
      acc[1][0] = mfma_bf16(a1, b0, acc[1][0]);
      acc[1][1] = mfma_bf16(a1, b1, acc[1][1]);
    }
    __syncthreads();
  }
  const int b = bh >> 3, h = bh & 7;
#pragma unroll
  for (int i = 0; i < 2; ++i)
#pragma unroll
    for (int j = 0; j < 2; ++j) {
      const int d = h * HD + wc + 16 * j + (l & 15);
#pragma unroll
      for (int r = 0; r < 4; ++r) {
        const int q = q0 + wr + 16 * i + ((l >> 4) << 2) + r;
        size_t o = ((size_t)(b * SEQ + q)) * EMB + d;
        u16 hi, lo; f2hl(acc[i][j][r], hi, lo);
        ctx_hi[o] = hi; ctx_lo[o] = lo;
      }
    }
}

// ---------------- K4: out = ctx @ Wo^T + bo (bf16x3 MFMA) ----------------
__global__ __launch_bounds__(256, 4) void oproj_kernel(
    const u16* __restrict__ ctx_hi, const u16* __restrict__ ctx_lo,
    const u16* __restrict__ WoH, const u16* __restrict__ WoL,
    const float* __restrict__ bo, float* __restrict__ out) {
  const int mt = blockIdx.x, ct = blockIdx.y;
  const int m0 = mt * 64, c0 = ct * 64;
  __shared__ u16 AH[64][40], AL[64][40], BH[64][40], BL[64][40];
  const int t = threadIdx.x, w = t >> 6, l = t & 63;
  const int wr = (w >> 1) * 32, wc = (w & 1) * 32;
  f32x4 acc[2][2] = {};
  const int srow = t >> 2, sc = (t & 3) * 8;
  for (int e0 = 0; e0 < EMB; e0 += 32) {
    *(bf16x8*)&AH[srow][sc] = *(const bf16x8*)&ctx_hi[(size_t)(m0 + srow) * EMB + e0 + sc];
    *(bf16x8*)&AL[srow][sc] = *(const bf16x8*)&ctx_lo[(size_t)(m0 + srow) * EMB + e0 + sc];
    *(bf16x8*)&BH[srow][sc] = *(const bf16x8*)&WoH[(size_t)(c0 + srow) * EMB + e0 + sc];
    *(bf16x8*)&BL[srow][sc] = *(const bf16x8*)&WoL[(size_t)(c0 + srow) * EMB + e0 + sc];
    __syncthreads();
    const int ar = l & 15, ach = (l >> 4) << 3;
    bf16x8 ah0 = *(bf16x8*)&AH[wr + ar][ach],      ah1 = *(bf16x8*)&AH[wr + 16 + ar][ach];
    bf16x8 al0 = *(bf16x8*)&AL[wr + ar][ach],      al1 = *(bf16x8*)&AL[wr + 16 + ar][ach];
    bf16x8 bh0 = *(bf16x8*)&BH[wc + ar][ach],      bh1 = *(bf16x8*)&BH[wc + 16 + ar][ach];
    bf16x8 bl0 = *(bf16x8*)&BL[wc + ar][ach],      bl1 = *(bf16x8*)&BL[wc + 16 + ar][ach];
    acc[0][0] = mfma_bf16(ah0, bh0, acc[0][0]); acc[0][0] = mfma_bf16(ah0, bl0, acc[0][0]); acc[0][0] = mfma_bf16(al0, bh0, acc[0][0]);
    acc[0][1] = mfma_bf16(ah0, bh1, acc[0][1]); acc[0][1] = mfma_bf16(ah0, bl1, acc[0][1]); acc[0][1] = mfma_bf16(al0, bh1, acc[0][1]);
    acc[1][0] = mfma_bf16(ah1, bh0, acc[1][0]); acc[1][0] = mfma_bf16(ah1, bl0, acc[1][0]); acc[1][0] = mfma_bf16(al1, bh0, acc[1][0]);
    acc[1][1] = mfma_bf16(ah1, bh1, acc[1][1]); acc[1][1] = mfma_bf16(ah1, bl1, acc[1][1]); acc[1][1] = mfma_bf16(al1, bh1, acc[1][1]);
    __syncthreads();
  }
#pragma unroll
  for (int i = 0; i < 2; ++i)
#pragma unroll
    for (int j = 0; j < 2; ++j) {
      const int col = c0 + wc + 16 * j + (l & 15);
      const float bias = bo[col];
#pragma unroll
      for (int r = 0; r < 4; ++r) {
        const int m = m0 + wr + 16 * i + ((l >> 4) << 2) + r;
        out[(size_t)m * EMB + col] = acc[i][j][r] + bias;
      }
    }
}

extern "C" void kernel_launch(void* const* d_in, const int* in_sizes, int n_in,
                              void* d_out, int out_size, void* d_ws, size_t ws_size,
                              hipStream_t stream) {
  const float* x = (const float*)d_in[0];
  const float* u = (const float*)d_in[1];
  const int* umask = (const int*)d_in[2];
  const float* Wq = (const float*)d_in[3];
  const float* Wk = (const float*)d_in[4];
  const float* Wv = (const float*)d_in[5];
  const float* Wu = (const float*)d_in[6];
  const float* bu = (const float*)d_in[7];
  const float* Wo = (const float*)d_in[8];
  const float* bo = (const float*)d_in[9];

  float* out = (float*)d_out;
  float* attn = out + (size_t)BSZ * SEQ * EMB;

  const size_t per = (size_t)BSZ * NH * SEQ * HD;  // 4,194,304
  u16* ws = (u16*)d_ws;
  u16* Qhi = ws;
  u16* Qlo = Qhi + per;
  u16* Khi = Qlo + per;
  u16* Klo = Khi + per;
  u16* Vt = Klo + per;
  u16* ctx_hi = Vt + per;
  u16* ctx_lo = ctx_hi + per;
  u16* Wsp = ctx_lo + per;  // [4][2][262144]

  const int wn4 = 262144 / 4;
  split_kernel<<<dim3(wn4 / 256), 256, 0, stream>>>(Wq, Wsp + 0 * 524288, Wsp + 0 * 524288 + 262144, wn4);
  split_kernel<<<dim3(wn4 / 256), 256, 0, stream>>>(Wk, Wsp + 1 * 524288, Wsp + 1 * 524288 + 262144, wn4);
  split_kernel<<<dim3(wn4 / 256), 256, 0, stream>>>(Wv, Wsp + 2 * 524288, Wsp + 2 * 524288 + 262144, wn4);
  split_kernel<<<dim3(wn4 / 256), 256, 0, stream>>>(Wo, Wsp + 3 * 524288, Wsp + 3 * 524288 + 262144, wn4);

  qkv_mfma_kernel<<<dim3(128, 8, 3), 256, 0, stream>>>(x, Wsp, Qhi, Qlo, Khi, Klo, Vt);
  scores_kernel<<<dim3(16, 16, 8), 256, 0, stream>>>(Qhi, Qlo, Khi, Klo, u, umask, Wu, bu, attn);
  pv_softmax_kernel<<<dim3(16, 64), 256, 0, stream>>>(attn, Vt, ctx_hi, ctx_lo);
  oproj_kernel<<<dim3(128, 8), 256, 0, stream>>>(ctx_hi, ctx_lo, Wsp + 3 * 524288, Wsp + 3 * 524288 + 262144, bo, out);
}

// Round 4
// 427.312 us; speedup vs baseline: 2.2991x; 1.2747x over previous
//
#include <hip/hip_runtime.h>
#include <hip/hip_bf16.h>
#include <math.h>

#define BSZ 8
#define SEQ 1024
#define EMB 512
#define NH 8
#define HD 64
#define UE 6
#define QKSCALE 0.125f

typedef unsigned short u16;
typedef short bf16x8 __attribute__((ext_vector_type(8)));
typedef float f32x4 __attribute__((ext_vector_type(4)));
typedef unsigned short ushort4_t __attribute__((ext_vector_type(4)));

__device__ __forceinline__ u16 f2bf(float f) {
  unsigned u = __float_as_uint(f);
  unsigned r = (u + 0x7fffu + ((u >> 16) & 1u)) >> 16;
  return (u16)r;
}
__device__ __forceinline__ void f2hl(float f, u16& hi, u16& lo) {
  hi = f2bf(f);
  float fh = __uint_as_float(((unsigned)hi) << 16);
  lo = f2bf(f - fh);
}
// vector-lane safe variant (clang can't bind refs to vector elements)
#define F2HL_V(fv, hv, lv, idx)            \
  {                                        \
    u16 _h, _l;                            \
    f2hl((fv), _h, _l);                    \
    (hv)[idx] = (short)_h;                 \
    (lv)[idx] = (short)_l;                 \
  }
__device__ __forceinline__ f32x4 mfma_bf16(bf16x8 a, bf16x8 b, f32x4 c) {
  return __builtin_amdgcn_mfma_f32_16x16x32_bf16(a, b, c, 0, 0, 0);
}

// ---------------- K0: split f32 -> (hi,lo) bf16 ----------------
__global__ __launch_bounds__(256) void split_kernel(const float* __restrict__ src,
                                                    u16* __restrict__ hi, u16* __restrict__ lo, int n4) {
  int i = blockIdx.x * 256 + threadIdx.x;
  if (i >= n4) return;
  float4 v = ((const float4*)src)[i];
  ushort4_t h, l;
  F2HL_V(v.x, h, l, 0); F2HL_V(v.y, h, l, 1);
  F2HL_V(v.z, h, l, 2); F2HL_V(v.w, h, l, 3);
  ((ushort4_t*)hi)[i] = h;
  ((ushort4_t*)lo)[i] = l;
}

// ---------------- K1: QKV projection (bf16x3 MFMA) ----------------
// grid (mt 128, h 8, wsel 3). Q/K -> hi/lo bf16 [bh][n][64]; V -> transposed bf16 Vt[bh][d][n]
__global__ __launch_bounds__(256, 2) void qkv_mfma_kernel(
    const float* __restrict__ x, const u16* __restrict__ Wsp,
    u16* __restrict__ Qhi, u16* __restrict__ Qlo,
    u16* __restrict__ Khi, u16* __restrict__ Klo, u16* __restrict__ Vt) {
  const int mt = blockIdx.x, h = blockIdx.y, wsel = blockIdx.z;
  const int m0 = mt * 64, c0 = h * 64;
  const u16* __restrict__ WH = Wsp + (size_t)wsel * 524288;
  const u16* __restrict__ WL = WH + 262144;
  __shared__ u16 AH[64][40], AL[64][40], BH[64][40], BL[64][40];
  __shared__ u16 vout[64][69];
  const int t = threadIdx.x, w = t >> 6, l = t & 63;
  const int wr = (w >> 1) * 32, wc = (w & 1) * 32;
  f32x4 acc[2][2] = {};
  const int srow = t >> 2;
  for (int e0 = 0; e0 < EMB; e0 += 32) {
    {
      const int c = (t & 3) * 8;
      float4 v0 = *(const float4*)&x[(size_t)(m0 + srow) * EMB + e0 + c];
      float4 v1 = *(const float4*)&x[(size_t)(m0 + srow) * EMB + e0 + c + 4];
      ushort4_t h0, l0, h1, l1;
      F2HL_V(v0.x, h0, l0, 0); F2HL_V(v0.y, h0, l0, 1); F2HL_V(v0.z, h0, l0, 2); F2HL_V(v0.w, h0, l0, 3);
      F2HL_V(v1.x, h1, l1, 0); F2HL_V(v1.y, h1, l1, 1); F2HL_V(v1.z, h1, l1, 2); F2HL_V(v1.w, h1, l1, 3);
      *(ushort4_t*)&AH[srow][c] = h0; *(ushort4_t*)&AH[srow][c + 4] = h1;
      *(ushort4_t*)&AL[srow][c] = l0; *(ushort4_t*)&AL[srow][c + 4] = l1;
      *(bf16x8*)&BH[srow][c] = *(const bf16x8*)&WH[(size_t)(c0 + srow) * EMB + e0 + c];
      *(bf16x8*)&BL[srow][c] = *(const bf16x8*)&WL[(size_t)(c0 + srow) * EMB + e0 + c];
    }
    __syncthreads();
    const int ar = l & 15, ach = (l >> 4) << 3;
    bf16x8 ah0 = *(bf16x8*)&AH[wr + ar][ach],      ah1 = *(bf16x8*)&AH[wr + 16 + ar][ach];
    bf16x8 al0 = *(bf16x8*)&AL[wr + ar][ach],      al1 = *(bf16x8*)&AL[wr + 16 + ar][ach];
    bf16x8 bh0 = *(bf16x8*)&BH[wc + ar][ach],      bh1 = *(bf16x8*)&BH[wc + 16 + ar][ach];
    bf16x8 bl0 = *(bf16x8*)&BL[wc + ar][ach],      bl1 = *(bf16x8*)&BL[wc + 16 + ar][ach];
    acc[0][0] = mfma_bf16(ah0, bh0, acc[0][0]); acc[0][0] = mfma_bf16(ah0, bl0, acc[0][0]); acc[0][0] = mfma_bf16(al0, bh0, acc[0][0]);
    acc[0][1] = mfma_bf16(ah0, bh1, acc[0][1]); acc[0][1] = mfma_bf16(ah0, bl1, acc[0][1]); acc[0][1] = mfma_bf16(al0, bh1, acc[0][1]);
    acc[1][0] = mfma_bf16(ah1, bh0, acc[1][0]); acc[1][0] = mfma_bf16(ah1, bl0, acc[1][0]); acc[1][0] = mfma_bf16(al1, bh0, acc[1][0]);
    acc[1][1] = mfma_bf16(ah1, bh1, acc[1][1]); acc[1][1] = mfma_bf16(ah1, bl1, acc[1][1]); acc[1][1] = mfma_bf16(al1, bh1, acc[1][1]);
    __syncthreads();
  }
  const int bb = m0 >> 10, n0 = m0 & 1023;
  if (wsel < 2) {
    u16* __restrict__ OH = wsel ? Khi : Qhi;
    u16* __restrict__ OL = wsel ? Klo : Qlo;
#pragma unroll
    for (int i = 0; i < 2; ++i)
#pragma unroll
      for (int j = 0; j < 2; ++j) {
        const int col = wc + 16 * j + (l & 15);
#pragma unroll
        for (int r = 0; r < 4; ++r) {
          const int n = n0 + wr + 16 * i + ((l >> 4) << 2) + r;
          size_t o = ((size_t)(bb * NH + h) * SEQ + n) * HD + col;
          u16 hi, lo; f2hl(acc[i][j][r], hi, lo);
          OH[o] = hi; OL[o] = lo;
        }
      }
  } else {
#pragma unroll
    for (int i = 0; i < 2; ++i)
#pragma unroll
      for (int j = 0; j < 2; ++j) {
        const int col = wc + 16 * j + (l & 15);
#pragma unroll
        for (int r = 0; r < 4; ++r)
          vout[wr + 16 * i + ((l >> 4) << 2) + r][col] = f2bf(acc[i][j][r]);
      }
    __syncthreads();
    const int d = t >> 2, nch = (t & 3) * 16;
    bf16x8 o0, o1;
#pragma unroll
    for (int i = 0; i < 8; ++i) o0[i] = (short)vout[nch + i][d];
#pragma unroll
    for (int i = 0; i < 8; ++i) o1[i] = (short)vout[nch + 8 + i][d];
    size_t dst = ((size_t)(bb * NH + h) * HD + d) * SEQ + n0 + nch;
    *(bf16x8*)&Vt[dst] = o0;
    *(bf16x8*)&Vt[dst + 8] = o1;
  }
}

// ---------------- K2: raw scores = QK^T*scale + ub (masked) ----------------
// grid (kt 16, qt 16, b 8); all 8 heads per block; u read once into registers.
// (256,2): avoid the 64-VGPR spill cliff (upk alone is 48 VGPRs).
__global__ __launch_bounds__(256, 2) void scores_kernel(
    const u16* __restrict__ Qhi, const u16* __restrict__ Qlo,
    const u16* __restrict__ Khi, const u16* __restrict__ Klo,
    const float* __restrict__ u, const int* __restrict__ umask,
    const float* __restrict__ Wu, const float* __restrict__ bu,
    float* __restrict__ attn) {
  const int kt = blockIdx.x, qt = blockIdx.y, b = blockIdx.z;
  const int q0 = qt * 64, k0 = kt * 64;
  __shared__ u16 KsH[64][72], KsL[64][72];
  __shared__ unsigned char ms[64][68];
  const int t = threadIdx.x, w = t >> 6, l = t & 63;
  const int qb = 16 * w + ((l >> 4) << 2);  // per-lane row base (4 rows)
  const int kl = l & 15;

  // mask tile: ms[k][q] = umask[b][k0+k][q0+q]
#pragma unroll
  for (int r = 0; r < 16; ++r) {
    int idx = r * 256 + t; int k = idx >> 6, q = idx & 63;
    ms[k][q] = (unsigned char)(umask[((size_t)b * SEQ + k0 + k) * SEQ + q0 + q] != 0);
  }

  // u preload -> packed bf16 pairs (rows 2p,2p+1); lives in regs across h-loop
  unsigned upk[UE][4][2];
  {
    const float* ubase = u + ((size_t)b * UE * SEQ + q0 + qb) * SEQ + k0 + kl;
#pragma unroll
    for (int uu = 0; uu < UE; ++uu)
#pragma unroll
      for (int tt = 0; tt < 4; ++tt)
#pragma unroll
        for (int p = 0; p < 2; ++p) {
          const float* up = ubase + (size_t)uu * SEQ * SEQ + (size_t)(2 * p) * SEQ + 16 * tt;
          float f0 = up[0], f1 = up[SEQ];
          upk[uu][tt][p] = (unsigned)f2bf(f0) | ((unsigned)f2bf(f1) << 16);
        }
  }

  // K prefetch for h=0
  const int krow_s = t >> 2, kc_s = (t & 3) * 16;
  bf16x8 kpre0, kpre1, kpre2, kpre3;
  {
    const u16* kp = Khi + ((size_t)(b * NH) * SEQ + k0 + krow_s) * HD + kc_s;
    const u16* kq = Klo + ((size_t)(b * NH) * SEQ + k0 + krow_s) * HD + kc_s;
    kpre0 = *(const bf16x8*)kp; kpre1 = *(const bf16x8*)(kp + 8);
    kpre2 = *(const bf16x8*)kq; kpre3 = *(const bf16x8*)(kq + 8);
  }

  for (int h = 0; h < NH; ++h) {
    const int bh = b * NH + h;
    __syncthreads();  // previous iteration's LDS readers done
    *(bf16x8*)&KsH[krow_s][kc_s] = kpre0;
    *(bf16x8*)&KsH[krow_s][kc_s + 8] = kpre1;
    *(bf16x8*)&KsL[krow_s][kc_s] = kpre2;
    *(bf16x8*)&KsL[krow_s][kc_s + 8] = kpre3;
    if (h < NH - 1) {  // prefetch next head's K tile (latency hidden under MFMA phase)
      const u16* kp = Khi + ((size_t)(bh + 1) * SEQ + k0 + krow_s) * HD + kc_s;
      const u16* kq = Klo + ((size_t)(bh + 1) * SEQ + k0 + krow_s) * HD + kc_s;
      kpre0 = *(const bf16x8*)kp; kpre1 = *(const bf16x8*)(kp + 8);
      kpre2 = *(const bf16x8*)kq; kpre3 = *(const bf16x8*)(kq + 8);
    }
    __syncthreads();  // staging visible

    const u16* qp = Qhi + ((size_t)bh * SEQ + q0 + 16 * w + (l & 15)) * HD + ((l >> 4) << 3);
    const u16* ql = Qlo + ((size_t)bh * SEQ + q0 + 16 * w + (l & 15)) * HD + ((l >> 4) << 3);
    bf16x8 qh0 = *(const bf16x8*)qp, qh1 = *(const bf16x8*)(qp + 32);
    bf16x8 ql0 = *(const bf16x8*)ql, ql1 = *(const bf16x8*)(ql + 32);
    float wu_[UE];
#pragma unroll
    for (int uu = 0; uu < UE; ++uu) wu_[uu] = Wu[h * UE + uu];
    const float bub = bu[h];
    float* abase = attn + ((size_t)bh * SEQ + q0 + qb) * SEQ + k0 + kl;
#pragma unroll
    for (int tt = 0; tt < 4; ++tt) {
      const int krow = tt * 16 + (l & 15), kch = (l >> 4) << 3;
      bf16x8 kh0 = *(bf16x8*)&KsH[krow][kch], kh1 = *(bf16x8*)&KsH[krow][kch + 32];
      bf16x8 kl0 = *(bf16x8*)&KsL[krow][kch], kl1 = *(bf16x8*)&KsL[krow][kch + 32];
      f32x4 acc = {0.f, 0.f, 0.f, 0.f};
      acc = mfma_bf16(qh0, kh0, acc); acc = mfma_bf16(qh1, kh1, acc);
      acc = mfma_bf16(qh0, kl0, acc); acc = mfma_bf16(qh1, kl1, acc);
      acc = mfma_bf16(ql0, kh0, acc); acc = mfma_bf16(ql1, kh1, acc);
#pragma unroll
      for (int p = 0; p < 2; ++p) {
        float ubx = bub, uby = bub;
#pragma unroll
        for (int uu = 0; uu < UE; ++uu) {
          unsigned pk = upk[uu][tt][p];
          float flo = __uint_as_float(pk << 16);
          float fhi = __uint_as_float(pk & 0xffff0000u);
          ubx = fmaf(wu_[uu], flo, ubx);
          uby = fmaf(wu_[uu], fhi, uby);
        }
#pragma unroll
        for (int e = 0; e < 2; ++e) {
          const int r = 2 * p + e;
          float v = acc[r] * QKSCALE + (e ? uby : ubx);
          if (ms[tt * 16 + kl][qb + r]) v = -INFINITY;
          abase[(size_t)r * SEQ + tt * 16] = v;  // direct coalesced-by-16 store
        }
      }
    }
  }
}

// ---------------- K3: fused softmax + PV ----------------
// grid (qt 16, bh 64). attn: raw in, softmax out (in place). ctx -> hi/lo bf16.
__global__ __launch_bounds__(256, 2) void pv_softmax_kernel(
    float* __restrict__ attn, const u16* __restrict__ Vt,
    u16* __restrict__ ctx_hi, u16* __restrict__ ctx_lo) {
  const int qt = blockIdx.x, bh = blockIdx.y;
  const int q0 = qt * 64;
  __shared__ u16 Pl[64][72], Vs[64][72];
  const int t = threadIdx.x, w = t >> 6, l = t & 63;
  const int row = t >> 2, cc = (t & 3) * 16;
  float* arow = attn + ((size_t)bh * SEQ + q0 + row) * SEQ + cc;

  // phase 1: per-row online max & sum (4 threads per row)
  float M = -INFINITY, S = 0.f;
  for (int k0 = 0; k0 < SEQ; k0 += 64) {
    float4 v0 = *(const float4*)(arow + k0);
    float4 v1 = *(const float4*)(arow + k0 + 4);
    float4 v2 = *(const float4*)(arow + k0 + 8);
    float4 v3 = *(const float4*)(arow + k0 + 12);
    float tm = fmaxf(fmaxf(fmaxf(v0.x, v0.y), fmaxf(v0.z, v0.w)),
                     fmaxf(fmaxf(v1.x, v1.y), fmaxf(v1.z, v1.w)));
    tm = fmaxf(tm, fmaxf(fmaxf(fmaxf(v2.x, v2.y), fmaxf(v2.z, v2.w)),
                         fmaxf(fmaxf(v3.x, v3.y), fmaxf(v3.z, v3.w))));
    if (tm > M) { S *= __expf(M - tm); M = tm; }
    S += __expf(v0.x - M) + __expf(v0.y - M) + __expf(v0.z - M) + __expf(v0.w - M)
       + __expf(v1.x - M) + __expf(v1.y - M) + __expf(v1.z - M) + __expf(v1.w - M)
       + __expf(v2.x - M) + __expf(v2.y - M) + __expf(v2.z - M) + __expf(v2.w - M)
       + __expf(v3.x - M) + __expf(v3.y - M) + __expf(v3.z - M) + __expf(v3.w - M);
  }
#pragma unroll
  for (int o = 1; o <= 2; o <<= 1) {
    float Mo = __shfl_xor(M, o), So = __shfl_xor(S, o);
    float Mn = fmaxf(M, Mo);
    S = S * __expf(M - Mn) + So * __expf(Mo - Mn);
    M = Mn;
  }
  const float inv = 1.0f / S;

  // phase 2: normalize + write attn + MFMA PV
  const int wr = (w >> 1) * 32, wc = (w & 1) * 32;
  f32x4 acc[2][2] = {};
  for (int k0 = 0; k0 < SEQ; k0 += 64) {
    bf16x8 p0, p1;
#pragma unroll
    for (int c4 = 0; c4 < 4; ++c4) {
      float4 v = *(const float4*)(arow + k0 + 4 * c4);
      float4 p;
      p.x = __expf(v.x - M) * inv; p.y = __expf(v.y - M) * inv;
      p.z = __expf(v.z - M) * inv; p.w = __expf(v.w - M) * inv;
      *(float4*)(arow + k0 + 4 * c4) = p;
      if (c4 < 2) {
        p0[4 * c4 + 0] = (short)f2bf(p.x); p0[4 * c4 + 1] = (short)f2bf(p.y);
        p0[4 * c4 + 2] = (short)f2bf(p.z); p0[4 * c4 + 3] = (short)f2bf(p.w);
      } else {
        p1[4 * (c4 - 2) + 0] = (short)f2bf(p.x); p1[4 * (c4 - 2) + 1] = (short)f2bf(p.y);
        p1[4 * (c4 - 2) + 2] = (short)f2bf(p.z); p1[4 * (c4 - 2) + 3] = (short)f2bf(p.w);
      }
    }
    *(bf16x8*)&Pl[row][cc] = p0;
    *(bf16x8*)&Pl[row][cc + 8] = p1;
    {
      const u16* vp = Vt + ((size_t)bh * HD + row) * SEQ + k0 + cc;
      *(bf16x8*)&Vs[row][cc] = *(const bf16x8*)vp;
      *(bf16x8*)&Vs[row][cc + 8] = *(const bf16x8*)(vp + 8);
    }
    __syncthreads();
#pragma unroll
    for (int kb = 0; kb < 2; ++kb) {
      const int kch = kb * 32 + ((l >> 4) << 3);
      bf16x8 a0 = *(bf16x8*)&Pl[wr + (l & 15)][kch];
      bf16x8 a1 = *(bf16x8*)&Pl[wr + 16 + (l & 15)][kch];
      bf16x8 b0 = *(bf16x8*)&Vs[wc + (l & 15)][kch];
      bf16x8 b1 = *(bf16x8*)&Vs[wc + 16 + (l & 15)][kch];
      acc[0][0] = mfma_bf16(a0, b0, acc[0][0]);
      acc[0][1] = mfma_bf16(a0, b1, acc[0][1]);
      acc[1][0] = mfma_bf16(a1, b0, acc[1][0]);
      acc[1][1] = mfma_bf16(a1, b1, acc[1][1]);
    }
    __syncthreads();
  }
  const int b = bh >> 3, h = bh & 7;
#pragma unroll
  for (int i = 0; i < 2; ++i)
#pragma unroll
    for (int j = 0; j < 2; ++j) {
      const int d = h * HD + wc + 16 * j + (l & 15);
#pragma unroll
      for (int r = 0; r < 4; ++r) {
        const int q = q0 + wr + 16 * i + ((l >> 4) << 2) + r;
        size_t o = ((size_t)(b * SEQ + q)) * EMB + d;
        u16 hi, lo; f2hl(acc[i][j][r], hi, lo);
        ctx_hi[o] = hi; ctx_lo[o] = lo;
      }
    }
}

// ---------------- K4: out = ctx @ Wo^T + bo (bf16x3 MFMA) ----------------
__global__ __launch_bounds__(256, 2) void oproj_kernel(
    const u16* __restrict__ ctx_hi, const u16* __restrict__ ctx_lo,
    const u16* __restrict__ WoH, const u16* __restrict__ WoL,
    const float* __restrict__ bo, float* __restrict__ out) {
  const int mt = blockIdx.x, ct = blockIdx.y;
  const int m0 = mt * 64, c0 = ct * 64;
  __shared__ u16 AH[64][40], AL[64][40], BH[64][40], BL[64][40];
  const int t = threadIdx.x, w = t >> 6, l = t & 63;
  const int wr = (w >> 1) * 32, wc = (w & 1) * 32;
  f32x4 acc[2][2] = {};
  const int srow = t >> 2, sc = (t & 3) * 8;
  for (int e0 = 0; e0 < EMB; e0 += 32) {
    *(bf16x8*)&AH[srow][sc] = *(const bf16x8*)&ctx_hi[(size_t)(m0 + srow) * EMB + e0 + sc];
    *(bf16x8*)&AL[srow][sc] = *(const bf16x8*)&ctx_lo[(size_t)(m0 + srow) * EMB + e0 + sc];
    *(bf16x8*)&BH[srow][sc] = *(const bf16x8*)&WoH[(size_t)(c0 + srow) * EMB + e0 + sc];
    *(bf16x8*)&BL[srow][sc] = *(const bf16x8*)&WoL[(size_t)(c0 + srow) * EMB + e0 + sc];
    __syncthreads();
    const int ar = l & 15, ach = (l >> 4) << 3;
    bf16x8 ah0 = *(bf16x8*)&AH[wr + ar][ach],      ah1 = *(bf16x8*)&AH[wr + 16 + ar][ach];
    bf16x8 al0 = *(bf16x8*)&AL[wr + ar][ach],      al1 = *(bf16x8*)&AL[wr + 16 + ar][ach];
    bf16x8 bh0 = *(bf16x8*)&BH[wc + ar][ach],      bh1 = *(bf16x8*)&BH[wc + 16 + ar][ach];
    bf16x8 bl0 = *(bf16x8*)&BL[wc + ar][ach],      bl1 = *(bf16x8*)&BL[wc + 16 + ar][ach];
    acc[0][0] = mfma_bf16(ah0, bh0, acc[0][0]); acc[0][0] = mfma_bf16(ah0, bl0, acc[0][0]); acc[0][0] = mfma_bf16(al0, bh0, acc[0][0]);
    acc[0][1] = mfma_bf16(ah0, bh1, acc[0][1]); acc[0][1] = mfma_bf16(ah0, bl1, acc[0][1]); acc[0][1] = mfma_bf16(al0, bh1, acc[0][1]);
    acc[1][0] = mfma_bf16(ah1, bh0, acc[1][0]); acc[1][0] = mfma_bf16(ah1, bl0, acc[1][0]); acc[1][0] = mfma_bf16(al1, bh0, acc[1][0]);
    acc[1][1] = mfma_bf16(ah1, bh1, acc[1][1]); acc[1][1] = mfma_bf16(ah1, bl1, acc[1][1]); acc[1][1] = mfma_bf16(al1, bh1, acc[1][1]);
    __syncthreads();
  }
#pragma unroll
  for (int i = 0; i < 2; ++i)
#pragma unroll
    for (int j = 0; j < 2; ++j) {
      const int col = c0 + wc + 16 * j + (l & 15);
      const float bias = bo[col];
#pragma unroll
      for (int r = 0; r < 4; ++r) {
        const int m = m0 + wr + 16 * i + ((l >> 4) << 2) + r;
        out[(size_t)m * EMB + col] = acc[i][j][r] + bias;
      }
    }
}

extern "C" void kernel_launch(void* const* d_in, const int* in_sizes, int n_in,
                              void* d_out, int out_size, void* d_ws, size_t ws_size,
                              hipStream_t stream) {
  const float* x = (const float*)d_in[0];
  const float* u = (const float*)d_in[1];
  const int* umask = (const int*)d_in[2];
  const float* Wq = (const float*)d_in[3];
  const float* Wk = (const float*)d_in[4];
  const float* Wv = (const float*)d_in[5];
  const float* Wu = (const float*)d_in[6];
  const float* bu = (const float*)d_in[7];
  const float* Wo = (const float*)d_in[8];
  const float* bo = (const float*)d_in[9];

  float* out = (float*)d_out;
  float* attn = out + (size_t)BSZ * SEQ * EMB;

  const size_t per = (size_t)BSZ * NH * SEQ * HD;  // 4,194,304
  u16* ws = (u16*)d_ws;
  u16* Qhi = ws;
  u16* Qlo = Qhi + per;
  u16* Khi = Qlo + per;
  u16* Klo = Khi + per;
  u16* Vt = Klo + per;
  u16* ctx_hi = Vt + per;
  u16* ctx_lo = ctx_hi + per;
  u16* Wsp = ctx_lo + per;  // [4][2][262144]

  const int wn4 = 262144 / 4;
  split_kernel<<<dim3(wn4 / 256), 256, 0, stream>>>(Wq, Wsp + 0 * 524288, Wsp + 0 * 524288 + 262144, wn4);
  split_kernel<<<dim3(wn4 / 256), 256, 0, stream>>>(Wk, Wsp + 1 * 524288, Wsp + 1 * 524288 + 262144, wn4);
  split_kernel<<<dim3(wn4 / 256), 256, 0, stream>>>(Wv, Wsp + 2 * 524288, Wsp + 2 * 524288 + 262144, wn4);
  split_kernel<<<dim3(wn4 / 256), 256, 0, stream>>>(Wo, Wsp + 3 * 524288, Wsp + 3 * 524288 + 262144, wn4);

  qkv_mfma_kernel<<<dim3(128, 8, 3), 256, 0, stream>>>(x, Wsp, Qhi, Qlo, Khi, Klo, Vt);
  scores_kernel<<<dim3(16, 16, 8), 256, 0, stream>>>(Qhi, Qlo, Khi, Klo, u, umask, Wu, bu, attn);
  pv_softmax_kernel<<<dim3(16, 64), 256, 0, stream>>>(attn, Vt, ctx_hi, ctx_lo);
  oproj_kernel<<<dim3(128, 8), 256, 0, stream>>>(ctx_hi, ctx_lo, Wsp + 3 * 524288, Wsp + 3 * 524288 + 262144, bo, out);
}

// Round 5
// 421.735 us; speedup vs baseline: 2.3295x; 1.0132x over previous
//
#include <hip/hip_runtime.h>
#include <hip/hip_bf16.h>
#include <math.h>

#define BSZ 8
#define SEQ 1024
#define EMB 512
#define NH 8
#define HD 64
#define UE 6
#define QKSCALE 0.125f

typedef unsigned short u16;
typedef short bf16x8 __attribute__((ext_vector_type(8)));
typedef float f32x4 __attribute__((ext_vector_type(4)));
typedef unsigned short ushort4_t __attribute__((ext_vector_type(4)));

__device__ __forceinline__ u16 f2bf(float f) {
  unsigned u = __float_as_uint(f);
  unsigned r = (u + 0x7fffu + ((u >> 16) & 1u)) >> 16;
  return (u16)r;
}
__device__ __forceinline__ void f2hl(float f, u16& hi, u16& lo) {
  hi = f2bf(f);
  float fh = __uint_as_float(((unsigned)hi) << 16);
  lo = f2bf(f - fh);
}
// vector-lane safe variant (clang can't bind refs to vector elements)
#define F2HL_V(fv, hv, lv, idx)            \
  {                                        \
    u16 _h, _l;                            \
    f2hl((fv), _h, _l);                    \
    (hv)[idx] = (short)_h;                 \
    (lv)[idx] = (short)_l;                 \
  }
__device__ __forceinline__ f32x4 mfma_bf16(bf16x8 a, bf16x8 b, f32x4 c) {
  return __builtin_amdgcn_mfma_f32_16x16x32_bf16(a, b, c, 0, 0, 0);
}

// ---------------- K0: split f32 -> (hi,lo) bf16 ----------------
__global__ __launch_bounds__(256) void split_kernel(const float* __restrict__ src,
                                                    u16* __restrict__ hi, u16* __restrict__ lo, int n4) {
  int i = blockIdx.x * 256 + threadIdx.x;
  if (i >= n4) return;
  float4 v = ((const float4*)src)[i];
  ushort4_t h, l;
  F2HL_V(v.x, h, l, 0); F2HL_V(v.y, h, l, 1);
  F2HL_V(v.z, h, l, 2); F2HL_V(v.w, h, l, 3);
  ((ushort4_t*)hi)[i] = h;
  ((ushort4_t*)lo)[i] = l;
}

// ---------------- K1: QKV projection (bf16x3 MFMA) ----------------
// grid (mt 128, h 8, wsel 3). Q/K -> hi/lo bf16 [bh][n][64]; V -> transposed bf16 Vt[bh][d][n]
__global__ __launch_bounds__(256, 2) void qkv_mfma_kernel(
    const float* __restrict__ x, const u16* __restrict__ Wsp,
    u16* __restrict__ Qhi, u16* __restrict__ Qlo,
    u16* __restrict__ Khi, u16* __restrict__ Klo, u16* __restrict__ Vt) {
  const int mt = blockIdx.x, h = blockIdx.y, wsel = blockIdx.z;
  const int m0 = mt * 64, c0 = h * 64;
  const u16* __restrict__ WH = Wsp + (size_t)wsel * 524288;
  const u16* __restrict__ WL = WH + 262144;
  __shared__ u16 AH[64][40], AL[64][40], BH[64][40], BL[64][40];
  __shared__ u16 vout[64][69];
  const int t = threadIdx.x, w = t >> 6, l = t & 63;
  const int wr = (w >> 1) * 32, wc = (w & 1) * 32;
  f32x4 acc[2][2] = {};
  const int srow = t >> 2;
  for (int e0 = 0; e0 < EMB; e0 += 32) {
    {
      const int c = (t & 3) * 8;
      float4 v0 = *(const float4*)&x[(size_t)(m0 + srow) * EMB + e0 + c];
      float4 v1 = *(const float4*)&x[(size_t)(m0 + srow) * EMB + e0 + c + 4];
      ushort4_t h0, l0, h1, l1;
      F2HL_V(v0.x, h0, l0, 0); F2HL_V(v0.y, h0, l0, 1); F2HL_V(v0.z, h0, l0, 2); F2HL_V(v0.w, h0, l0, 3);
      F2HL_V(v1.x, h1, l1, 0); F2HL_V(v1.y, h1, l1, 1); F2HL_V(v1.z, h1, l1, 2); F2HL_V(v1.w, h1, l1, 3);
      *(ushort4_t*)&AH[srow][c] = h0; *(ushort4_t*)&AH[srow][c + 4] = h1;
      *(ushort4_t*)&AL[srow][c] = l0; *(ushort4_t*)&AL[srow][c + 4] = l1;
      *(bf16x8*)&BH[srow][c] = *(const bf16x8*)&WH[(size_t)(c0 + srow) * EMB + e0 + c];
      *(bf16x8*)&BL[srow][c] = *(const bf16x8*)&WL[(size_t)(c0 + srow) * EMB + e0 + c];
    }
    __syncthreads();
    const int ar = l & 15, ach = (l >> 4) << 3;
    bf16x8 ah0 = *(bf16x8*)&AH[wr + ar][ach],      ah1 = *(bf16x8*)&AH[wr + 16 + ar][ach];
    bf16x8 al0 = *(bf16x8*)&AL[wr + ar][ach],      al1 = *(bf16x8*)&AL[wr + 16 + ar][ach];
    bf16x8 bh0 = *(bf16x8*)&BH[wc + ar][ach],      bh1 = *(bf16x8*)&BH[wc + 16 + ar][ach];
    bf16x8 bl0 = *(bf16x8*)&BL[wc + ar][ach],      bl1 = *(bf16x8*)&BL[wc + 16 + ar][ach];
    acc[0][0] = mfma_bf16(ah0, bh0, acc[0][0]); acc[0][0] = mfma_bf16(ah0, bl0, acc[0][0]); acc[0][0] = mfma_bf16(al0, bh0, acc[0][0]);
    acc[0][1] = mfma_bf16(ah0, bh1, acc[0][1]); acc[0][1] = mfma_bf16(ah0, bl1, acc[0][1]); acc[0][1] = mfma_bf16(al0, bh1, acc[0][1]);
    acc[1][0] = mfma_bf16(ah1, bh0, acc[1][0]); acc[1][0] = mfma_bf16(ah1, bl0, acc[1][0]); acc[1][0] = mfma_bf16(al1, bh0, acc[1][0]);
    acc[1][1] = mfma_bf16(ah1, bh1, acc[1][1]); acc[1][1] = mfma_bf16(ah1, bl1, acc[1][1]); acc[1][1] = mfma_bf16(al1, bh1, acc[1][1]);
    __syncthreads();
  }
  const int bb = m0 >> 10, n0 = m0 & 1023;
  if (wsel < 2) {
    u16* __restrict__ OH = wsel ? Khi : Qhi;
    u16* __restrict__ OL = wsel ? Klo : Qlo;
#pragma unroll
    for (int i = 0; i < 2; ++i)
#pragma unroll
      for (int j = 0; j < 2; ++j) {
        const int col = wc + 16 * j + (l & 15);
#pragma unroll
        for (int r = 0; r < 4; ++r) {
          const int n = n0 + wr + 16 * i + ((l >> 4) << 2) + r;
          size_t o = ((size_t)(bb * NH + h) * SEQ + n) * HD + col;
          u16 hi, lo; f2hl(acc[i][j][r], hi, lo);
          OH[o] = hi; OL[o] = lo;
        }
      }
  } else {
#pragma unroll
    for (int i = 0; i < 2; ++i)
#pragma unroll
      for (int j = 0; j < 2; ++j) {
        const int col = wc + 16 * j + (l & 15);
#pragma unroll
        for (int r = 0; r < 4; ++r)
          vout[wr + 16 * i + ((l >> 4) << 2) + r][col] = f2bf(acc[i][j][r]);
      }
    __syncthreads();
    const int d = t >> 2, nch = (t & 3) * 16;
    bf16x8 o0, o1;
#pragma unroll
    for (int i = 0; i < 8; ++i) o0[i] = (short)vout[nch + i][d];
#pragma unroll
    for (int i = 0; i < 8; ++i) o1[i] = (short)vout[nch + 8 + i][d];
    size_t dst = ((size_t)(bb * NH + h) * HD + d) * SEQ + n0 + nch;
    *(bf16x8*)&Vt[dst] = o0;
    *(bf16x8*)&Vt[dst + 8] = o1;
  }
}

// ---------------- K2: raw scores + per-(row,ktile) softmax partials ----------------
// grid (kt 16, qt 16, b 8); all 8 heads per block; u read once into registers.
// pairs[bh][q][kt] = {tile max m, tile sum s = sum exp(v - m)} for flash-merge in K3.
__global__ __launch_bounds__(256, 2) void scores_kernel(
    const u16* __restrict__ Qhi, const u16* __restrict__ Qlo,
    const u16* __restrict__ Khi, const u16* __restrict__ Klo,
    const float* __restrict__ u, const int* __restrict__ umask,
    const float* __restrict__ Wu, const float* __restrict__ bu,
    float* __restrict__ attn, float2* __restrict__ pairs) {
  const int kt = blockIdx.x, qt = blockIdx.y, b = blockIdx.z;
  const int q0 = qt * 64, k0 = kt * 64;
  __shared__ u16 KsH[64][72], KsL[64][72];
  __shared__ unsigned char ms[64][68];
  const int t = threadIdx.x, w = t >> 6, l = t & 63;
  const int qb = 16 * w + ((l >> 4) << 2);  // per-lane row base (4 rows)
  const int kl = l & 15;

  // mask tile: ms[k][q] = umask[b][k0+k][q0+q]
#pragma unroll
  for (int r = 0; r < 16; ++r) {
    int idx = r * 256 + t; int k = idx >> 6, q = idx & 63;
    ms[k][q] = (unsigned char)(umask[((size_t)b * SEQ + k0 + k) * SEQ + q0 + q] != 0);
  }

  // u preload -> packed bf16 pairs (rows 2p,2p+1); lives in regs across h-loop
  unsigned upk[UE][4][2];
  {
    const float* ubase = u + ((size_t)b * UE * SEQ + q0 + qb) * SEQ + k0 + kl;
#pragma unroll
    for (int uu = 0; uu < UE; ++uu)
#pragma unroll
      for (int tt = 0; tt < 4; ++tt)
#pragma unroll
        for (int p = 0; p < 2; ++p) {
          const float* up = ubase + (size_t)uu * SEQ * SEQ + (size_t)(2 * p) * SEQ + 16 * tt;
          float f0 = up[0], f1 = up[SEQ];
          upk[uu][tt][p] = (unsigned)f2bf(f0) | ((unsigned)f2bf(f1) << 16);
        }
  }

  // K prefetch for h=0
  const int krow_s = t >> 2, kc_s = (t & 3) * 16;
  bf16x8 kpre0, kpre1, kpre2, kpre3;
  {
    const u16* kp = Khi + ((size_t)(b * NH) * SEQ + k0 + krow_s) * HD + kc_s;
    const u16* kq = Klo + ((size_t)(b * NH) * SEQ + k0 + krow_s) * HD + kc_s;
    kpre0 = *(const bf16x8*)kp; kpre1 = *(const bf16x8*)(kp + 8);
    kpre2 = *(const bf16x8*)kq; kpre3 = *(const bf16x8*)(kq + 8);
  }

  for (int h = 0; h < NH; ++h) {
    const int bh = b * NH + h;
    __syncthreads();  // previous iteration's LDS readers done
    *(bf16x8*)&KsH[krow_s][kc_s] = kpre0;
    *(bf16x8*)&KsH[krow_s][kc_s + 8] = kpre1;
    *(bf16x8*)&KsL[krow_s][kc_s] = kpre2;
    *(bf16x8*)&KsL[krow_s][kc_s + 8] = kpre3;
    if (h < NH - 1) {  // prefetch next head's K tile (latency hidden under MFMA phase)
      const u16* kp = Khi + ((size_t)(bh + 1) * SEQ + k0 + krow_s) * HD + kc_s;
      const u16* kq = Klo + ((size_t)(bh + 1) * SEQ + k0 + krow_s) * HD + kc_s;
      kpre0 = *(const bf16x8*)kp; kpre1 = *(const bf16x8*)(kp + 8);
      kpre2 = *(const bf16x8*)kq; kpre3 = *(const bf16x8*)(kq + 8);
    }
    __syncthreads();  // staging visible

    const u16* qp = Qhi + ((size_t)bh * SEQ + q0 + 16 * w + (l & 15)) * HD + ((l >> 4) << 3);
    const u16* ql = Qlo + ((size_t)bh * SEQ + q0 + 16 * w + (l & 15)) * HD + ((l >> 4) << 3);
    bf16x8 qh0 = *(const bf16x8*)qp, qh1 = *(const bf16x8*)(qp + 32);
    bf16x8 ql0 = *(const bf16x8*)ql, ql1 = *(const bf16x8*)(ql + 32);
    float wu_[UE];
#pragma unroll
    for (int uu = 0; uu < UE; ++uu) wu_[uu] = Wu[h * UE + uu];
    const float bub = bu[h];
    float* abase = attn + ((size_t)bh * SEQ + q0 + qb) * SEQ + k0 + kl;

    float sv[4][4];  // [r][tt]
#pragma unroll
    for (int tt = 0; tt < 4; ++tt) {
      const int krow = tt * 16 + (l & 15), kch = (l >> 4) << 3;
      bf16x8 kh0 = *(bf16x8*)&KsH[krow][kch], kh1 = *(bf16x8*)&KsH[krow][kch + 32];
      bf16x8 kl0 = *(bf16x8*)&KsL[krow][kch], kl1 = *(bf16x8*)&KsL[krow][kch + 32];
      f32x4 acc = {0.f, 0.f, 0.f, 0.f};
      acc = mfma_bf16(qh0, kh0, acc); acc = mfma_bf16(qh1, kh1, acc);
      acc = mfma_bf16(qh0, kl0, acc); acc = mfma_bf16(qh1, kl1, acc);
      acc = mfma_bf16(ql0, kh0, acc); acc = mfma_bf16(ql1, kh1, acc);
#pragma unroll
      for (int p = 0; p < 2; ++p) {
        float ubx = bub, uby = bub;
#pragma unroll
        for (int uu = 0; uu < UE; ++uu) {
          unsigned pk = upk[uu][tt][p];
          float flo = __uint_as_float(pk << 16);
          float fhi = __uint_as_float(pk & 0xffff0000u);
          ubx = fmaf(wu_[uu], flo, ubx);
          uby = fmaf(wu_[uu], fhi, uby);
        }
        sv[2 * p + 0][tt] = ms[tt * 16 + kl][qb + 2 * p + 0] ? -INFINITY : acc[2 * p + 0] * QKSCALE + ubx;
        sv[2 * p + 1][tt] = ms[tt * 16 + kl][qb + 2 * p + 1] ? -INFINITY : acc[2 * p + 1] * QKSCALE + uby;
      }
    }
    // raw stores
#pragma unroll
    for (int r = 0; r < 4; ++r)
#pragma unroll
      for (int tt = 0; tt < 4; ++tt)
        abase[(size_t)r * SEQ + tt * 16] = sv[r][tt];
    // per-(row, ktile) softmax partials: reduce over 4 local + 16 kl lanes
#pragma unroll
    for (int r = 0; r < 4; ++r) {
      float m = fmaxf(fmaxf(sv[r][0], sv[r][1]), fmaxf(sv[r][2], sv[r][3]));
#pragma unroll
      for (int o = 1; o <= 8; o <<= 1) m = fmaxf(m, __shfl_xor(m, o));
      float s = __expf(sv[r][0] - m) + __expf(sv[r][1] - m) +
                __expf(sv[r][2] - m) + __expf(sv[r][3] - m);
#pragma unroll
      for (int o = 1; o <= 8; o <<= 1) s += __shfl_xor(s, o);
      if (kl == 0)
        pairs[((size_t)bh * SEQ + q0 + qb + r) * 16 + kt] = make_float2(m, s);
    }
  }
}

// ---------------- K3: single-pass normalize + PV ----------------
// grid (qt 16, bh 64). Merges per-ktile (m,s) pairs, then one streaming pass:
// read raw attn -> p=exp(v-M)*inv -> write normalized -> bf16 LDS -> PV MFMA.
__global__ __launch_bounds__(256, 2) void pv_softmax_kernel(
    float* __restrict__ attn, const u16* __restrict__ Vt,
    const float2* __restrict__ pairs, u16* __restrict__ ctx) {
  const int qt = blockIdx.x, bh = blockIdx.y;
  const int q0 = qt * 64;
  __shared__ u16 Pl[64][72], Vs[64][72];
  const int t = threadIdx.x, w = t >> 6, l = t & 63;
  const int row = t >> 2, cc = (t & 3) * 16;
  float* arow = attn + ((size_t)bh * SEQ + q0 + row) * SEQ + cc;

  // merge 16 tile-pairs (4 per thread, then 4-lane shfl merge)
  float M = -INFINITY, S = 0.f;
  {
    const float2* pp = pairs + ((size_t)bh * SEQ + q0 + row) * 16 + (t & 3) * 4;
#pragma unroll
    for (int j = 0; j < 4; ++j) {
      float2 c = pp[j];
      float Mn = fmaxf(M, c.x);
      S = S * __expf(M - Mn) + c.y * __expf(c.x - Mn);
      M = Mn;
    }
#pragma unroll
    for (int o = 1; o <= 2; o <<= 1) {
      float Mo = __shfl_xor(M, o), So = __shfl_xor(S, o);
      float Mn = fmaxf(M, Mo);
      S = S * __expf(M - Mn) + So * __expf(Mo - Mn);
      M = Mn;
    }
  }
  const float inv = 1.0f / S;

  const int wr = (w >> 1) * 32, wc = (w & 1) * 32;
  f32x4 acc[2][2] = {};
  // preload chunk 0 (attn + V) into regs
  float4 va0 = *(const float4*)(arow + 0), va1 = *(const float4*)(arow + 4);
  float4 va2 = *(const float4*)(arow + 8), va3 = *(const float4*)(arow + 12);
  const u16* vrow = Vt + ((size_t)bh * HD + row) * SEQ + cc;
  bf16x8 vb0 = *(const bf16x8*)vrow, vb1 = *(const bf16x8*)(vrow + 8);

  for (int k0 = 0; k0 < SEQ; k0 += 64) {
    bf16x8 p0, p1;
    float4 p;
    p.x = __expf(va0.x - M) * inv; p.y = __expf(va0.y - M) * inv;
    p.z = __expf(va0.z - M) * inv; p.w = __expf(va0.w - M) * inv;
    *(float4*)(arow + k0 + 0) = p;
    p0[0] = (short)f2bf(p.x); p0[1] = (short)f2bf(p.y); p0[2] = (short)f2bf(p.z); p0[3] = (short)f2bf(p.w);
    p.x = __expf(va1.x - M) * inv; p.y = __expf(va1.y - M) * inv;
    p.z = __expf(va1.z - M) * inv; p.w = __expf(va1.w - M) * inv;
    *(float4*)(arow + k0 + 4) = p;
    p0[4] = (short)f2bf(p.x); p0[5] = (short)f2bf(p.y); p0[6] = (short)f2bf(p.z); p0[7] = (short)f2bf(p.w);
    p.x = __expf(va2.x - M) * inv; p.y = __expf(va2.y - M) * inv;
    p.z = __expf(va2.z - M) * inv; p.w = __expf(va2.w - M) * inv;
    *(float4*)(arow + k0 + 8) = p;
    p1[0] = (short)f2bf(p.x); p1[1] = (short)f2bf(p.y); p1[2] = (short)f2bf(p.z); p1[3] = (short)f2bf(p.w);
    p.x = __expf(va3.x - M) * inv; p.y = __expf(va3.y - M) * inv;
    p.z = __expf(va3.z - M) * inv; p.w = __expf(va3.w - M) * inv;
    *(float4*)(arow + k0 + 12) = p;
    p1[4] = (short)f2bf(p.x); p1[5] = (short)f2bf(p.y); p1[6] = (short)f2bf(p.z); p1[7] = (short)f2bf(p.w);

    *(bf16x8*)&Pl[row][cc] = p0;
    *(bf16x8*)&Pl[row][cc + 8] = p1;
    *(bf16x8*)&Vs[row][cc] = vb0;
    *(bf16x8*)&Vs[row][cc + 8] = vb1;

    if (k0 + 64 < SEQ) {  // prefetch next chunk before barrier: HBM hides under MFMA
      va0 = *(const float4*)(arow + k0 + 64);
      va1 = *(const float4*)(arow + k0 + 68);
      va2 = *(const float4*)(arow + k0 + 72);
      va3 = *(const float4*)(arow + k0 + 76);
      vb0 = *(const bf16x8*)(vrow + k0 + 64);
      vb1 = *(const bf16x8*)(vrow + k0 + 72);
    }
    __syncthreads();
#pragma unroll
    for (int kb = 0; kb < 2; ++kb) {
      const int kch = kb * 32 + ((l >> 4) << 3);
      bf16x8 a0 = *(bf16x8*)&Pl[wr + (l & 15)][kch];
      bf16x8 a1 = *(bf16x8*)&Pl[wr + 16 + (l & 15)][kch];
      bf16x8 b0 = *(bf16x8*)&Vs[wc + (l & 15)][kch];
      bf16x8 b1 = *(bf16x8*)&Vs[wc + 16 + (l & 15)][kch];
      acc[0][0] = mfma_bf16(a0, b0, acc[0][0]);
      acc[0][1] = mfma_bf16(a0, b1, acc[0][1]);
      acc[1][0] = mfma_bf16(a1, b0, acc[1][0]);
      acc[1][1] = mfma_bf16(a1, b1, acc[1][1]);
    }
    __syncthreads();
  }
  const int b = bh >> 3, h = bh & 7;
#pragma unroll
  for (int i = 0; i < 2; ++i)
#pragma unroll
    for (int j = 0; j < 2; ++j) {
      const int d = h * HD + wc + 16 * j + (l & 15);
#pragma unroll
      for (int r = 0; r < 4; ++r) {
        const int q = q0 + wr + 16 * i + ((l >> 4) << 2) + r;
        ctx[((size_t)(b * SEQ + q)) * EMB + d] = f2bf(acc[i][j][r]);
      }
    }
}

// ---------------- K4: out = ctx(bf16) @ Wo^T(hi/lo) + bo ----------------
__global__ __launch_bounds__(256, 2) void oproj_kernel(
    const u16* __restrict__ ctx,
    const u16* __restrict__ WoH, const u16* __restrict__ WoL,
    const float* __restrict__ bo, float* __restrict__ out) {
  const int mt = blockIdx.x, ct = blockIdx.y;
  const int m0 = mt * 64, c0 = ct * 64;
  __shared__ u16 AH[64][40], BH[64][40], BL[64][40];
  const int t = threadIdx.x, w = t >> 6, l = t & 63;
  const int wr = (w >> 1) * 32, wc = (w & 1) * 32;
  f32x4 acc[2][2] = {};
  const int srow = t >> 2, sc = (t & 3) * 8;
  for (int e0 = 0; e0 < EMB; e0 += 32) {
    *(bf16x8*)&AH[srow][sc] = *(const bf16x8*)&ctx[(size_t)(m0 + srow) * EMB + e0 + sc];
    *(bf16x8*)&BH[srow][sc] = *(const bf16x8*)&WoH[(size_t)(c0 + srow) * EMB + e0 + sc];
    *(bf16x8*)&BL[srow][sc] = *(const bf16x8*)&WoL[(size_t)(c0 + srow) * EMB + e0 + sc];
    __syncthreads();
    const int ar = l & 15, ach = (l >> 4) << 3;
    bf16x8 ah0 = *(bf16x8*)&AH[wr + ar][ach],      ah1 = *(bf16x8*)&AH[wr + 16 + ar][ach];
    bf16x8 bh0 = *(bf16x8*)&BH[wc + ar][ach],      bh1 = *(bf16x8*)&BH[wc + 16 + ar][ach];
    bf16x8 bl0 = *(bf16x8*)&BL[wc + ar][ach],      bl1 = *(bf16x8*)&BL[wc + 16 + ar][ach];
    acc[0][0] = mfma_bf16(ah0, bh0, acc[0][0]); acc[0][0] = mfma_bf16(ah0, bl0, acc[0][0]);
    acc[0][1] = mfma_bf16(ah0, bh1, acc[0][1]); acc[0][1] = mfma_bf16(ah0, bl1, acc[0][1]);
    acc[1][0] = mfma_bf16(ah1, bh0, acc[1][0]); acc[1][0] = mfma_bf16(ah1, bl0, acc[1][0]);
    acc[1][1] = mfma_bf16(ah1, bh1, acc[1][1]); acc[1][1] = mfma_bf16(ah1, bl1, acc[1][1]);
    __syncthreads();
  }
#pragma unroll
  for (int i = 0; i < 2; ++i)
#pragma unroll
    for (int j = 0; j < 2; ++j) {
      const int col = c0 + wc + 16 * j + (l & 15);
      const float bias = bo[col];
#pragma unroll
      for (int r = 0; r < 4; ++r) {
        const int m = m0 + wr + 16 * i + ((l >> 4) << 2) + r;
        out[(size_t)m * EMB + col] = acc[i][j][r] + bias;
      }
    }
}

extern "C" void kernel_launch(void* const* d_in, const int* in_sizes, int n_in,
                              void* d_out, int out_size, void* d_ws, size_t ws_size,
                              hipStream_t stream) {
  const float* x = (const float*)d_in[0];
  const float* u = (const float*)d_in[1];
  const int* umask = (const int*)d_in[2];
  const float* Wq = (const float*)d_in[3];
  const float* Wk = (const float*)d_in[4];
  const float* Wv = (const float*)d_in[5];
  const float* Wu = (const float*)d_in[6];
  const float* bu = (const float*)d_in[7];
  const float* Wo = (const float*)d_in[8];
  const float* bo = (const float*)d_in[9];

  float* out = (float*)d_out;
  float* attn = out + (size_t)BSZ * SEQ * EMB;

  const size_t per = (size_t)BSZ * NH * SEQ * HD;  // 4,194,304
  u16* ws = (u16*)d_ws;
  u16* Qhi = ws;
  u16* Qlo = Qhi + per;
  u16* Khi = Qlo + per;
  u16* Klo = Khi + per;
  u16* Vt = Klo + per;
  u16* ctx = Vt + per;
  float2* pairs = (float2*)(ctx + per);                      // 64*1024*16 float2 = 8.39MB
  u16* Wsp = (u16*)((char*)pairs + (size_t)BSZ * NH * SEQ * 16 * sizeof(float2));
  // total: 6*8.39 + 8.39 + 4.19 = 62.9 MB

  const int wn4 = 262144 / 4;
  split_kernel<<<dim3(wn4 / 256), 256, 0, stream>>>(Wq, Wsp + 0 * 524288, Wsp + 0 * 524288 + 262144, wn4);
  split_kernel<<<dim3(wn4 / 256), 256, 0, stream>>>(Wk, Wsp + 1 * 524288, Wsp + 1 * 524288 + 262144, wn4);
  split_kernel<<<dim3(wn4 / 256), 256, 0, stream>>>(Wv, Wsp + 2 * 524288, Wsp + 2 * 524288 + 262144, wn4);
  split_kernel<<<dim3(wn4 / 256), 256, 0, stream>>>(Wo, Wsp + 3 * 524288, Wsp + 3 * 524288 + 262144, wn4);

  qkv_mfma_kernel<<<dim3(128, 8, 3), 256, 0, stream>>>(x, Wsp, Qhi, Qlo, Khi, Klo, Vt);
  scores_kernel<<<dim3(16, 16, 8), 256, 0, stream>>>(Qhi, Qlo, Khi, Klo, u, umask, Wu, bu, attn, pairs);
  pv_softmax_kernel<<<dim3(16, 64), 256, 0, stream>>>(attn, Vt, pairs, ctx);
  oproj_kernel<<<dim3(128, 8), 256, 0, stream>>>(ctx, Wsp + 3 * 524288, Wsp + 3 * 524288 + 262144, bo, out);
}